// Round 7
// baseline (333.914 us; speedup 1.0000x reference)
//
#include <hip/hip_runtime.h>
#include <hip/hip_bf16.h>

typedef unsigned short u16;
typedef __attribute__((ext_vector_type(4))) float f32x4;
typedef __attribute__((ext_vector_type(16))) float f32x16;
typedef __attribute__((ext_vector_type(8))) short s16x8;
typedef __attribute__((ext_vector_type(2))) unsigned u32x2;

constexpr int DMODEL = 1024;
constexpr int NH     = 16;
constexpr int DK     = 64;
constexpr int SEQ    = 4096;
constexpr int BATCH  = 2;
constexpr int BS     = BATCH * SEQ;     // 8192
constexpr int NX     = BS * DMODEL;     // 8,388,608
constexpr int NW     = DMODEL * DMODEL; // 1,048,576

__device__ __forceinline__ u16 f2bf(float f) {
  union { float f; unsigned u; } v; v.f = f;
  unsigned r = v.u + 0x7fffu + ((v.u >> 16) & 1u);
  return (u16)(r >> 16);
}
__device__ __forceinline__ float bf2f(u16 h) {
  union { unsigned u; float f; } v; v.u = ((unsigned)h) << 16;
  return v.f;
}
__device__ __forceinline__ unsigned fbits(float f) { union { float f; unsigned u; } v; v.f = f; return v.u; }
__device__ __forceinline__ float bitsf(unsigned u) { union { unsigned u; float f; } v; v.u = u; return v.f; }
__device__ __forceinline__ unsigned pk2(float a, float b) {
  float2 t; t.x = a; t.y = b;
  __hip_bfloat162 h = __float22bfloat162_rn(t);
  return *reinterpret_cast<unsigned*>(&h);
}
__device__ __forceinline__ u32x2 plswap(unsigned a, unsigned b) {
  return __builtin_amdgcn_permlane32_swap(a, b, false, false);
}
__device__ __forceinline__ f32x16 mfma32(s16x8 a, s16x8 b, f32x16 c) {
  return __builtin_amdgcn_mfma_f32_32x32x16_bf16(a, b, c, 0, 0, 0);
}
__device__ __forceinline__ void gload_lds16(const void* g, void* l) {
  __builtin_amdgcn_global_load_lds(
      (const __attribute__((address_space(1))) void*)g,
      (__attribute__((address_space(3))) void*)l, 16, 0, 0);
}

// ---------------- fp32 -> bf16 conversion for x and W[qkvo] ----------------
__global__ __launch_bounds__(256) void convert_all(
    const float* __restrict__ x, const float* __restrict__ wq,
    const float* __restrict__ wk, const float* __restrict__ wv,
    const float* __restrict__ wo, u16* __restrict__ xb, u16* __restrict__ Wb) {
  int t = blockIdx.x * 256 + threadIdx.x;
  int i = t * 4;
  const float* src; u16* dst;
  if (i < NX) { src = x + i; dst = xb + i; }
  else {
    int j = i - NX; int w = j >> 20; int jj = j & (NW - 1);
    src = (w == 0 ? wq : w == 1 ? wk : w == 2 ? wv : wo) + jj;
    dst = Wb + j;
  }
  float4 v = *reinterpret_cast<const float4*>(src);
  uint2 pk; pk.x = pk2(v.x, v.y); pk.y = pk2(v.z, v.w);
  *reinterpret_cast<uint2*>(dst) = pk;
}

// ---------------- 128x128 bf16 GEMM, C = A * B^T (B rows = output cols) ----
template <int EPI>
__global__ __launch_bounds__(256) void gemm128(
    const u16* __restrict__ A, const u16* __restrict__ B,
    u16* __restrict__ Qw, u16* __restrict__ Kw, u16* __restrict__ Vt,
    float* __restrict__ Co) {
  __shared__ u16 lA[128 * 32];
  __shared__ u16 lB[128 * 32];
  const int tid = threadIdx.x, w = tid >> 6, l = tid & 63;
  const int wr = w >> 1, wc = w & 1;
  const int m0 = blockIdx.y * 128, n0 = blockIdx.x * 128;
  constexpr int K = 1024;
  f32x4 acc[4][4] = {};
  const int li = l & 15, lg = l >> 4;
  const int srow = l >> 2, skc = (l & 3) * 8;
  for (int k0 = 0; k0 < K; k0 += 32) {
    __syncthreads();
#pragma unroll
    for (int cc = 0; cc < 2; ++cc) {
      const int c = 2 * w + cc;
      const int row = c * 16 + srow;
      gload_lds16(A + (size_t)(m0 + row) * K + k0 + skc, &lA[c * 512]);
      gload_lds16(B + (size_t)(n0 + row) * K + k0 + skc, &lB[c * 512]);
    }
    __syncthreads();
    s16x8 af[4], bfr[4];
#pragma unroll
    for (int i = 0; i < 4; ++i)
      af[i] = *reinterpret_cast<const s16x8*>(&lA[(wr * 64 + i * 16 + li) * 32 + lg * 8]);
#pragma unroll
    for (int j = 0; j < 4; ++j)
      bfr[j] = *reinterpret_cast<const s16x8*>(&lB[(wc * 64 + j * 16 + li) * 32 + lg * 8]);
#pragma unroll
    for (int i = 0; i < 4; ++i)
#pragma unroll
      for (int j = 0; j < 4; ++j)
        acc[i][j] = __builtin_amdgcn_mfma_f32_16x16x32_bf16(af[i], bfr[j], acc[i][j], 0, 0, 0);
  }
#pragma unroll
  for (int i = 0; i < 4; ++i) {
    const int mbase = m0 + wr * 64 + i * 16 + lg * 4;
#pragma unroll
    for (int j = 0; j < 4; ++j) {
      const int n = n0 + wc * 64 + j * 16 + li;
      if (EPI == 0) {
        const int which = n >> 10, nn = n & 1023, h = nn >> 6, d = nn & 63;
#pragma unroll
        for (int r = 0; r < 4; ++r) {
          const int m = mbase + r, b = m >> 12, s = m & (SEQ - 1);
          const int bh = b * NH + h;
          const u16 val = f2bf(acc[i][j][r]);
          if (which == 0)      Qw[((size_t)bh * SEQ + s) * DK + d] = val;
          else if (which == 1) Kw[((size_t)bh * SEQ + s) * DK + d] = val;
          else                 Vt[((size_t)bh * DK + d) * SEQ + s] = val;
        }
      } else {
#pragma unroll
        for (int r = 0; r < 4; ++r)
          Co[(size_t)(mbase + r) * DMODEL + n] = acc[i][j][r];
      }
    }
  }
}

// -------- RoPE in-place; Q additionally scaled by (1/8)*log2(e) for exp2 ---
__global__ __launch_bounds__(256) void rope_qk(u16* __restrict__ Qw, u16* __restrict__ Kw,
                                               const int* __restrict__ pos) {
  const int TOT = BATCH * NH * SEQ * 32;  // pairs per tensor
  int t = blockIdx.x * 256 + threadIdx.x;
  const bool isQ = (t < TOT);
  u16* arr = isQ ? Qw : Kw;
  int p = isQ ? t : t - TOT;
  const int i = p & 31;
  const int s = (p >> 5) & (SEQ - 1);
  const int bh = p >> 17;
  const float inv = expf(-(float)i * 0.28782313662425574f);
  const float ang = (float)pos[s] * inv;
  float sn, cs;
  sincosf(ang, &sn, &cs);
  const float sc = isQ ? 0.18033688011112042f : 1.0f;  // 0.125 * log2(e)
  u16* ptr = arr + ((size_t)bh * SEQ + s) * DK + 2 * i;
  unsigned v = *reinterpret_cast<unsigned*>(ptr);
  float xe = bf2f((u16)(v & 0xffffu)), xo = bf2f((u16)(v >> 16));
  float oe = (xe * cs - xo * sn) * sc;
  float oo = (xe * sn + xo * cs) * sc;
  *reinterpret_cast<unsigned*>(ptr) = pk2(oe, oo);
}

// ---------------- causal flash attention, 4 waves x 64 q-rows --------------
// 512 blocks (2/CU), 256 threads; each wave owns TWO 32-row q-strips that
// share one K/V fragment set -> LDS b128 reads per MFMA halve (16:32).
// Blocks are one 256-row q-tile each, launched heavy-first within each XCD
// chunk (LPT-style balance). KBLK=128, double-buffered via global_load_lds.
// Swapped MFMAs keep softmax lane-local (q = lane&31); score->PV fragment
// relayout via permlane32_swap; P never touches LDS.
__global__ __launch_bounds__(256, 2) void attn_kernel(
    const u16* __restrict__ Qw, const u16* __restrict__ Kw,
    const u16* __restrict__ Vt, u16* __restrict__ Ob) {
  __shared__ __align__(16) u16 Kb[2][8192];  // [128 k][128 B], XOR-swizzled
  __shared__ __align__(16) u16 Vb[2][8192];  // [64 d][256 B], XOR-swizzled
  const int tid = threadIdx.x, w = tid >> 6, l = tid & 63;
  const int lq = l & 31, hi = l >> 5;
  const int id = blockIdx.x;
  const int loc = id >> 3;
  const int bh = (id & 7) * 4 + (loc & 3);    // XCD-chunked: 4 heads per XCD
  const int t = 15 - (loc >> 2);              // heavy tiles first (LPT)
  const int niter = 2 * (t + 1);              // KBLK=128 iterations
  const u16* Qh = Qw + (size_t)bh * SEQ * DK;
  const u16* Kh = Kw + (size_t)bh * SEQ * DK;
  const u16* Vh = Vt + (size_t)bh * DK * SEQ;
  const int b = bh >> 4, h = bh & 15;
  const int qw = 256 * t + 64 * w;            // strips at qw, qw+32

  s16x8 aq[2][4];
#pragma unroll
  for (int st = 0; st < 2; ++st)
#pragma unroll
    for (int d4 = 0; d4 < 4; ++d4)
      aq[st][d4] = *reinterpret_cast<const s16x8*>(
          &Qh[(size_t)(qw + st * 32 + lq) * DK + d4 * 16 + hi * 8]);

  f32x16 o00 = {}, o01 = {}, o10 = {}, o11 = {};
  float mr0 = -1e30f, mr1 = -1e30f, lr0 = 0.f, lr1 = 0.f;

  auto stage = [&](int buf, int kt) {
    const int krow = tid >> 3;                                  // 0..31
    const int kcol = ((tid & 7) * 16) ^ ((krow & 7) << 4);
#pragma unroll
    for (int i = 0; i < 4; ++i)
      gload_lds16((const char*)Kh + (size_t)(kt + i * 32 + krow) * 128 + kcol,
                  (char*)&Kb[buf][0] + i * 4096 + tid * 16);
    const int vrow = tid >> 4;                                  // 0..15
    const int vcol = ((tid & 15) * 16) ^ ((vrow & 7) << 4);
#pragma unroll
    for (int i = 0; i < 4; ++i)
      gload_lds16((const char*)Vh + (size_t)(i * 16 + vrow) * (SEQ * 2) + kt * 2 + vcol,
                  (char*)&Vb[buf][0] + i * 4096 + tid * 16);
  };

  // strip softmax: mask, in-lane reduce + permlane, defer-max, exp2, pack,
  // and PV-fragment build (verified relayout from round 6)
  auto smax = [&](f32x16& sa, f32x16& sb, float& mr, float& lr,
                  f32x16& oa, f32x16& ob, s16x8* p, int qs, int ksub, bool diag) {
    if (diag) {
#pragma unroll
      for (int r = 0; r < 16; ++r) {
        const int kr = (r & 3) + 8 * (r >> 2) + 4 * hi;
        if (ksub + kr > qs + lq) sa[r] = -1e30f;
        if (ksub + 32 + kr > qs + lq) sb[r] = -1e30f;
      }
    }
    float mx = sa[0];
#pragma unroll
    for (int r = 1; r < 16; ++r) mx = fmaxf(mx, sa[r]);
#pragma unroll
    for (int r = 0; r < 16; ++r) mx = fmaxf(mx, sb[r]);
    {
      u32x2 pr = plswap(fbits(mx), fbits(mx));
      mx = fmaxf(bitsf(pr.x), bitsf(pr.y));
    }
    if (!__all(mx <= mr + 8.f)) {
      const float mn = fmaxf(mr, mx);
      const float fs = exp2f(mr - mn);
      mr = mn; lr *= fs;
      oa *= fs; ob *= fs;
    }
    float rs = 0.f;
#pragma unroll
    for (int r = 0; r < 16; ++r) { sa[r] = exp2f(sa[r] - mr); rs += sa[r]; }
#pragma unroll
    for (int r = 0; r < 16; ++r) { sb[r] = exp2f(sb[r] - mr); rs += sb[r]; }
    {
      u32x2 pr = plswap(fbits(rs), fbits(rs));
      rs = bitsf(pr.x) + bitsf(pr.y);
    }
    lr += rs;
    unsigned U0[8], U1[8];
#pragma unroll
    for (int m = 0; m < 4; ++m) {
      U0[m * 2 + 0] = pk2(sa[4 * m + 0], sa[4 * m + 1]);
      U0[m * 2 + 1] = pk2(sa[4 * m + 2], sa[4 * m + 3]);
      U1[m * 2 + 0] = pk2(sb[4 * m + 0], sb[4 * m + 1]);
      U1[m * 2 + 1] = pk2(sb[4 * m + 2], sb[4 * m + 3]);
    }
#pragma unroll
    for (int c16 = 0; c16 < 4; ++c16) {
      unsigned* U = (c16 < 2) ? U0 : U1;
      const int m0i = (c16 & 1) * 2, m1i = m0i + 1;
      u32x2 r0 = plswap(U[m0i * 2 + 0], U[m1i * 2 + 0]);
      u32x2 r1 = plswap(U[m0i * 2 + 1], U[m1i * 2 + 1]);
      union { uint4 u; s16x8 s; } cf;
      cf.u.x = r0.x; cf.u.y = r1.x; cf.u.z = r0.y; cf.u.w = r1.y;
      p[c16] = cf.s;
    }
  };

  auto writeO = [&](int qs, const f32x16& oa, const f32x16& ob, float lr) {
    const float inv = 1.f / lr;
    u16* orow = Ob + ((size_t)(b * SEQ + qs + lq)) * DMODEL + h * DK;
#pragma unroll
    for (int m = 0; m < 4; ++m) {
      uint2 pa;
      pa.x = pk2(oa[4 * m + 0] * inv, oa[4 * m + 1] * inv);
      pa.y = pk2(oa[4 * m + 2] * inv, oa[4 * m + 3] * inv);
      *reinterpret_cast<uint2*>(orow + 8 * m + 4 * hi) = pa;
      uint2 pb;
      pb.x = pk2(ob[4 * m + 0] * inv, ob[4 * m + 1] * inv);
      pb.y = pk2(ob[4 * m + 2] * inv, ob[4 * m + 3] * inv);
      *reinterpret_cast<uint2*>(orow + 32 + 8 * m + 4 * hi) = pb;
    }
  };

  stage(0, 0);
  for (int it = 0; it < niter; ++it) {
    asm volatile("s_waitcnt vmcnt(0)" ::: "memory");  // current buf staged
    __builtin_amdgcn_s_barrier();
    __builtin_amdgcn_sched_barrier(0);
    const int kt = 128 * it;
    stage((it + 1) & 1, (it + 1 < niter) ? kt + 128 : 0);
    const int cur = it & 1;
#pragma unroll
    for (int sub = 0; sub < 2; ++sub) {
      const int ksub = kt + 64 * sub;
      if (ksub > qw + 63) continue;          // both strips fully masked
      const bool do0 = (ksub <= qw + 31);    // lower strip has live rows
      const int sw = (lq & 7) << 4;
      // ---- K fragments (shared by both strips): 8 b128 reads
      s16x8 kf[2][4];
      const char* kbb = (const char*)&Kb[cur][0] + (size_t)(sub * 64 + lq) * 128;
#pragma unroll
      for (int kh = 0; kh < 2; ++kh)
#pragma unroll
        for (int d4 = 0; d4 < 4; ++d4)
          kf[kh][d4] = *reinterpret_cast<const s16x8*>(
              kbb + kh * 32 * 128 + ((d4 * 32 + hi * 16) ^ sw));
      // ---- QK^T: 16 mfma (8 when strip0 dead)
      f32x16 s00 = {}, s01 = {}, s10 = {}, s11 = {};
      __builtin_amdgcn_s_setprio(1);
#pragma unroll
      for (int d4 = 0; d4 < 4; ++d4) {
        if (do0) {
          s00 = mfma32(kf[0][d4], aq[0][d4], s00);
          s01 = mfma32(kf[1][d4], aq[0][d4], s01);
        }
        s10 = mfma32(kf[0][d4], aq[1][d4], s10);
        s11 = mfma32(kf[1][d4], aq[1][d4], s11);
      }
      __builtin_amdgcn_s_setprio(0);
      // ---- softmax per strip (independent chains -> ILP)
      s16x8 p0[4], p1[4];
      const bool dg0 = (ksub + 63 > qw), dg1 = (ksub + 63 > qw + 32);
      if (do0) smax(s00, s01, mr0, lr0, o00, o01, p0, qw, ksub, dg0);
      smax(s10, s11, mr1, lr1, o10, o11, p1, qw + 32, ksub, dg1);
      // ---- PV: 8 V reads, 16 mfma (8 when strip0 dead)
      const char* vbb = (const char*)&Vb[cur][0];
#pragma unroll
      for (int c16 = 0; c16 < 4; ++c16) {
        const int co = (sub * 128 + c16 * 32 + hi * 16) ^ sw;
        s16x8 v0 = *reinterpret_cast<const s16x8*>(vbb + (size_t)lq * 256 + co);
        s16x8 v1 = *reinterpret_cast<const s16x8*>(vbb + (size_t)(32 + lq) * 256 + co);
        __builtin_amdgcn_s_setprio(1);
        if (do0) {
          o00 = mfma32(v0, p0[c16], o00);
          o01 = mfma32(v1, p0[c16], o01);
        }
        o10 = mfma32(v0, p1[c16], o10);
        o11 = mfma32(v1, p1[c16], o11);
        __builtin_amdgcn_s_setprio(0);
      }
    }
  }
  writeO(qw, o00, o01, lr0);
  writeO(qw + 32, o10, o11, lr1);
}

extern "C" void kernel_launch(void* const* d_in, const int* in_sizes, int n_in,
                              void* d_out, int out_size, void* d_ws, size_t ws_size,
                              hipStream_t stream) {
  const float* x  = (const float*)d_in[0];
  const int*  pos = (const int*)d_in[1];
  const float* wq = (const float*)d_in[2];
  const float* wk = (const float*)d_in[3];
  const float* wv = (const float*)d_in[4];
  const float* wo = (const float*)d_in[5];
  float* out = (float*)d_out;

  u16* Wb = (u16*)d_ws;               // 4*NW bf16 (Wq|Wk|Wv|Wo)
  u16* xb = Wb + 4 * (size_t)NW;      // NX bf16
  u16* Qw = xb + (size_t)NX;          // (b,h,s,d)
  u16* Kw = Qw + (size_t)NX;          // (b,h,s,d)
  u16* Vt = Kw + (size_t)NX;          // (b,h,d,s)
  u16* Ab = xb;                       // reuse x-bf16 region for attn output

  convert_all<<<(NX + 4 * NW) / 4 / 256, 256, 0, stream>>>(x, wq, wk, wv, wo, xb, Wb);
  gemm128<0><<<dim3(24, 64), 256, 0, stream>>>(xb, Wb, Qw, Kw, Vt, nullptr);
  rope_qk<<<2 * (BATCH * NH * SEQ * 32) / 256, 256, 0, stream>>>(Qw, Kw, pos);
  attn_kernel<<<512, 256, 0, stream>>>(Qw, Kw, Vt, Ab);
  gemm128<1><<<dim3(8, 64), 256, 0, stream>>>(Ab, Wb + 3 * (size_t)NW, nullptr, nullptr, nullptr, out);
}